// Round 1
// baseline (375.582 us; speedup 1.0000x reference)
//
#include <hip/hip_runtime.h>

typedef int intx4 __attribute__((ext_vector_type(4)));
typedef int intx8 __attribute__((ext_vector_type(8)));
typedef float floatx4 __attribute__((ext_vector_type(4)));

#define M_DIM 8192
#define N_DIM 4096
#define K_DIM 4096
#define KB2 (K_DIM / 2)   // bytes per packed fp4 row

#define PACK_BLOCKS 2048
#define NF4_X ((size_t)M_DIM * K_DIM / 4)              // float4 count of x
#define NF4_TOT (NF4_X + (size_t)N_DIM * K_DIM / 4)    // + float4 count of W

// async global->LDS, 16B per lane. LDS dest is wave-uniform base + lane*16.
__device__ __forceinline__ void gld_lds16(const char* g, char* l) {
  __builtin_amdgcn_global_load_lds(
      (const __attribute__((address_space(1))) unsigned int*)g,
      (__attribute__((address_space(3))) unsigned int*)l,
      16, 0, 0);
}

// fp4 e2m1 sign nibble: +1 -> 0x2, -1 -> 0xA, 0 -> 0x0
__device__ __forceinline__ unsigned nib(float v) {
  return v > 0.0f ? 0x2u : (v < 0.0f ? 0xAu : 0x0u);
}

// Fully-coalesced pack: each lane-iteration reads ONE float4 (lanes contiguous
// -> 1KB per load instruction) and writes ONE ushort of 4 nibbles (lanes
// contiguous -> 128B per wave store). x occupies float4 indices [0, NF4_X),
// W the rest; packed outputs are contiguous (Wb directly follows Xb).
__global__ __launch_bounds__(256) void pack_kernel(const float* __restrict__ x,
                                                   const float* __restrict__ Wm,
                                                   unsigned short* __restrict__ pk,
                                                   double* __restrict__ accd) {
  const int t = threadIdx.x;
  const size_t stride = (size_t)PACK_BLOCKS * 256;
  const float4* __restrict__ X4 = (const float4*)x;
  const float4* __restrict__ W4 = (const float4*)Wm;
  float s = 0.0f;
  for (size_t i = (size_t)blockIdx.x * 256 + t; i < NF4_TOT; i += stride) {
    float4 v;
    if (i < NF4_X) {
      v = X4[i];
      s += fabsf(v.x) + fabsf(v.y) + fabsf(v.z) + fabsf(v.w);
    } else {
      v = W4[i - NF4_X];
    }
    pk[i] = (unsigned short)(nib(v.x) | (nib(v.y) << 4) | (nib(v.z) << 8) |
                             (nib(v.w) << 12));
  }
  #pragma unroll
  for (int off = 32; off > 0; off >>= 1) s += __shfl_down(s, off);
  __shared__ float sp[4];
  if ((t & 63) == 0) sp[t >> 6] = s;
  __syncthreads();
  if (t == 0) atomicAdd(accd, (double)(sp[0] + sp[1] + sp[2] + sp[3]));
}

// C = Xb (M x K, fp4) * Wb^T (N x K, fp4); out[m][n] = (dot + bias[n]) * scale
// 128x128 C tile / 4 waves / 4x4 subtiles of 16x16, BK=128 via mfma_scale
// 16x16x128 fp4 with unit scales. NOW 2-phase double-buffered (T3-min):
// issue next tile's global_load_lds BEFORE this tile's ds_read+MFMA; one
// vmcnt(0)+barrier (inside __syncthreads) per K-step, so stage latency hides
// under ~700 cycles of compute instead of being serially exposed.
//
// LDS layout per buffer (8 KB per matrix): row pairs interleaved into 128-B
// lines: addr(r, c) = (r>>1)*128 + c*32 + (r&1)*16. Slot c of row r holds
// global 16B k-chunk g = (c + (r>>1)) & 3 (swizzle applied on the global
// source address since global_load_lds destinations are lane-linear).
__global__ __launch_bounds__(256) void gemm_kernel(const char* __restrict__ Xb,
                                                   const char* __restrict__ Wb,
                                                   const float* __restrict__ bias,
                                                   const double* __restrict__ accd,
                                                   float* __restrict__ out) {
  __shared__ __align__(16) char ldsA[2][128 * 64];
  __shared__ __align__(16) char ldsB[2][128 * 64];
  const int t = threadIdx.x;
  const int lane = t & 63;
  const int w = t >> 6;            // wave 0..3
  const int m16 = lane & 15;
  const int quad = lane >> 4;      // 0..3 -> k-chunk of 32 fp4 (16 B)

  // XCD-aware bijective swizzle: 2048 blocks % 8 XCDs == 0. Hardware id i
  // lands on XCD i%8; give each XCD a contiguous 256-block chunk of work so
  // neighboring tiles (sharing Xb/Wb panels) hit the same L2.
  const int id = blockIdx.x;
  const int swz = (id & 7) * 256 + (id >> 3);
  const int bM = (swz >> 5) * 128;       // 64 M-tiles (slow axis)
  const int bN = (swz & 31) * 128;       // 32 N-tiles (fast axis)

  const int waveM = (w & 1) * 64;
  const int waveN = (w >> 1) * 64;
  // staging coords: thread t covers row rl = 2*(t>>3)+(t&1), slot sc=(t>>1)&3
  // (so LDS addr(rl,sc) == t*16, matching global_load_lds lane-linear dests)
  const int srl = 2 * (t >> 3) + (t & 1);
  const int ssc = (t >> 1) & 3;

  floatx4 acc[4][4];
  #pragma unroll
  for (int i = 0; i < 4; ++i)
    #pragma unroll
    for (int j = 0; j < 4; ++j)
      acc[i][j] = (floatx4){0.0f, 0.0f, 0.0f, 0.0f};

  auto stage = [&](int ki, int buf) {
    const size_t kb = (size_t)ki << 6;               // ki*64 bytes into the row
    #pragma unroll
    for (int rd = 0; rd < 2; ++rd) {
      const int r = rd * 64 + srl;                   // local row 0..127
      const int g = (ssc + (r >> 1)) & 3;            // global 16B chunk for slot
      const size_t goff = kb + (size_t)(g * 16);
      gld_lds16(Xb + (size_t)(bM + r) * KB2 + goff, &ldsA[buf][rd * 4096 + w * 1024]);
      gld_lds16(Wb + (size_t)(bN + r) * KB2 + goff, &ldsB[buf][rd * 4096 + w * 1024]);
    }
  };

  // prologue: fill buffer 0
  stage(0, 0);
  __syncthreads();                                   // drains vmcnt -> buf0 ready

  for (int ki = 0; ki < K_DIM / 128; ++ki) {
    const int cur = ki & 1;
    // issue next tile's loads into the other buffer FIRST (overlap with MFMA)
    if (ki + 1 < K_DIM / 128) stage(ki + 1, cur ^ 1);

    intx8 a8[4];
    #pragma unroll
    for (int i = 0; i < 4; ++i) {
      const int m = waveM + i * 16 + m16;            // A row (m = lane&15)
      const int c = (quad - (m >> 1)) & 3;           // slot holding chunk `quad`
      intx4 lo = *(const intx4*)&ldsA[cur][(m >> 1) * 128 + c * 32 + (m & 1) * 16];
      a8[i] = (intx8){lo[0], lo[1], lo[2], lo[3], 0, 0, 0, 0};
    }
    #pragma unroll
    for (int j = 0; j < 4; ++j) {
      const int n = waveN + j * 16 + m16;            // B row = output col
      const int c = (quad - (n >> 1)) & 3;
      intx4 lo = *(const intx4*)&ldsB[cur][(n >> 1) * 128 + c * 32 + (n & 1) * 16];
      intx8 b8 = (intx8){lo[0], lo[1], lo[2], lo[3], 0, 0, 0, 0};
      #pragma unroll
      for (int i = 0; i < 4; ++i)
        acc[i][j] = __builtin_amdgcn_mfma_scale_f32_16x16x128_f8f6f4(
            a8[i], b8, acc[i][j],
            4, 4,                       // cbsz=fp4(e2m1), blgp=fp4(e2m1)
            0, 0x7F7F7F7F,              // scale_a opsel, scales = 1.0
            0, 0x7F7F7F7F);             // scale_b opsel, scales = 1.0
    }
    // one drain per K-step: next-tile loads done AND this tile's ds_reads done
    __syncthreads();
  }

  const float scale = (float)(*accd * (1.0 / (double)((size_t)M_DIM * K_DIM)));

  // C/D layout (shape-determined, dtype-independent): col = lane&15, row = quad*4 + reg
  #pragma unroll
  for (int j = 0; j < 4; ++j) {
    const int col = bN + waveN + j * 16 + m16;
    const float bj = bias[col];
    #pragma unroll
    for (int i = 0; i < 4; ++i) {
      const size_t row0 = (size_t)(bM + waveM + i * 16 + quad * 4);
      float* po = out + row0 * N_DIM + col;
      #pragma unroll
      for (int r = 0; r < 4; ++r)
        po[(size_t)r * N_DIM] = (acc[i][j][r] + bj) * scale;
    }
  }
}

extern "C" void kernel_launch(void* const* d_in, const int* in_sizes, int n_in,
                              void* d_out, int out_size, void* d_ws, size_t ws_size,
                              hipStream_t stream) {
  const float* x = (const float*)d_in[0];   // [8192, 4096]
  const float* W = (const float*)d_in[1];   // [4096, 4096]
  const float* b = (const float*)d_in[2];   // [4096]
  float* out = (float*)d_out;               // [8192, 4096]

  double* accd = (double*)d_ws;                                   // 8B |x| sum
  char* Xb = (char*)d_ws + 256;                                   // 16 MiB sign(x) fp4
  char* Wb = (char*)d_ws + 256 + (size_t)M_DIM * K_DIM / 2;       // 8 MiB sign(W) fp4

  hipMemsetAsync(d_ws, 0, 8, stream);   // zero the reduction accumulator (ws is poisoned)
  pack_kernel<<<PACK_BLOCKS, 256, 0, stream>>>(x, W, (unsigned short*)Xb, accd);
  gemm_kernel<<<2048, 256, 0, stream>>>(Xb, Wb, b, accd, out);
}

// Round 2
// 358.174 us; speedup vs baseline: 1.0486x; 1.0486x over previous
//
#include <hip/hip_runtime.h>

typedef int intx4 __attribute__((ext_vector_type(4)));
typedef int intx8 __attribute__((ext_vector_type(8)));
typedef float floatx4 __attribute__((ext_vector_type(4)));

#define M_DIM 8192
#define N_DIM 4096
#define K_DIM 4096
#define KB2 (K_DIM / 2)   // bytes per packed fp4 row

#define PACK_BLOCKS 2048
#define NF4_X ((size_t)M_DIM * K_DIM / 4)              // float4 count of x
#define NF4_TOT (NF4_X + (size_t)N_DIM * K_DIM / 4)    // + float4 count of W

// async global->LDS, 16B per lane. LDS dest is wave-uniform base + lane*16.
__device__ __forceinline__ void gld_lds16(const char* g, char* l) {
  __builtin_amdgcn_global_load_lds(
      (const __attribute__((address_space(1))) unsigned int*)g,
      (__attribute__((address_space(3))) unsigned int*)l,
      16, 0, 0);
}

// fp4 e2m1 sign nibble: +1 -> 0x2, -1 -> 0xA, 0 -> 0x0
__device__ __forceinline__ unsigned nib(float v) {
  return v > 0.0f ? 0x2u : (v < 0.0f ? 0xAu : 0x0u);
}

// Fully-coalesced pack: each lane-iteration reads ONE float4 (lanes contiguous
// -> 1KB per load instruction) and writes ONE ushort of 4 nibbles (lanes
// contiguous -> 128B per wave store). x occupies float4 indices [0, NF4_X),
// W the rest; packed outputs are contiguous (Wb directly follows Xb).
__global__ __launch_bounds__(256) void pack_kernel(const float* __restrict__ x,
                                                   const float* __restrict__ Wm,
                                                   unsigned short* __restrict__ pk,
                                                   double* __restrict__ accd) {
  const int t = threadIdx.x;
  const size_t stride = (size_t)PACK_BLOCKS * 256;
  const float4* __restrict__ X4 = (const float4*)x;
  const float4* __restrict__ W4 = (const float4*)Wm;
  float s = 0.0f;
  for (size_t i = (size_t)blockIdx.x * 256 + t; i < NF4_TOT; i += stride) {
    float4 v;
    if (i < NF4_X) {
      v = X4[i];
      s += fabsf(v.x) + fabsf(v.y) + fabsf(v.z) + fabsf(v.w);
    } else {
      v = W4[i - NF4_X];
    }
    pk[i] = (unsigned short)(nib(v.x) | (nib(v.y) << 4) | (nib(v.z) << 8) |
                             (nib(v.w) << 12));
  }
  #pragma unroll
  for (int off = 32; off > 0; off >>= 1) s += __shfl_down(s, off);
  __shared__ float sp[4];
  if ((t & 63) == 0) sp[t >> 6] = s;
  __syncthreads();
  if (t == 0) atomicAdd(accd, (double)(sp[0] + sp[1] + sp[2] + sp[3]));
}

// C = Xb (M x K, fp4) * Wb^T (N x K, fp4); out[m][n] = (dot + bias[n]) * scale
// 128x128 C tile / 4 waves / 4x4 subtiles of 16x16, BK=128 via mfma_scale
// 16x16x128 fp4 with unit scales.
//
// 2-phase double-buffer, COMPILE-TIME buffer indices (manual x2 K-unroll):
//   STAGE(next tile, other buf) -> COMPUTE(this buf) -> __syncthreads()
// so the stage's HBM/L2 latency overlaps the 64 MFMAs instead of being
// serially exposed between two barriers. All ds_read offsets and global
// stage pointers are hoisted out of the loop (round-1 lesson: runtime
// buffer indexing doubled VALUBusy and sank MfmaUtil).
//
// Grid: reverted to round-0 2D mapping dim3(N/128, M/128) — proven 78 MB
// FETCH; the XCD chunk-swizzle doubled it (157 MB).
//
// LDS layout per buffer (8 KB per matrix): row pairs interleaved into 128-B
// lines: addr(r, c) = (r>>1)*128 + c*32 + (r&1)*16. Slot c of row r holds
// global 16B k-chunk g = (c + (r>>1)) & 3 (swizzle applied on the global
// source address since global_load_lds destinations are lane-linear).
__global__ __launch_bounds__(256) void gemm_kernel(const char* __restrict__ Xb,
                                                   const char* __restrict__ Wb,
                                                   const float* __restrict__ bias,
                                                   const double* __restrict__ accd,
                                                   float* __restrict__ out) {
  __shared__ __align__(16) char lA[2][8192];
  __shared__ __align__(16) char lB[2][8192];
  const int t = threadIdx.x;
  const int lane = t & 63;
  const int w = t >> 6;            // wave 0..3
  const int m16 = lane & 15;
  const int quad = lane >> 4;      // 0..3 -> k-chunk of 32 fp4 (16 B)
  const int bM = blockIdx.y * 128;
  const int bN = blockIdx.x * 128;
  const int waveM = (w & 1) * 64;
  const int waveN = (w >> 1) * 64;

  // staging: thread t covers local row srl, 16B slot ssc, so that LDS
  // addr(srl,ssc) == t*16 (matches global_load_lds lane-linear dests).
  // The swizzle chunk g = (ssc + (srl>>1))&3 is the same for srl and srl+64,
  // so it folds into the global base pointers (computed ONCE).
  const int srl = 2 * (t >> 3) + (t & 1);
  const int ssc = (t >> 1) & 3;
  const int g0 = (ssc + (srl >> 1)) & 3;
  const char* gA = Xb + (size_t)(bM + srl) * KB2 + g0 * 16;
  const char* gB = Wb + (size_t)(bN + srl) * KB2 + g0 * 16;
  const int ldst = w * 1024;       // wave-uniform LDS dest offset

  // per-wave ds_read byte offsets — loop-invariant, computed once
  int offA[4], offB[4];
  #pragma unroll
  for (int i = 0; i < 4; ++i) {
    const int m = waveM + i * 16 + m16;
    offA[i] = (m >> 1) * 128 + (((quad - (m >> 1)) & 3)) * 32 + (m & 1) * 16;
    const int n = waveN + i * 16 + m16;
    offB[i] = (n >> 1) * 128 + (((quad - (n >> 1)) & 3)) * 32 + (n & 1) * 16;
  }

  floatx4 acc[4][4];
  #pragma unroll
  for (int i = 0; i < 4; ++i)
    #pragma unroll
    for (int j = 0; j < 4; ++j)
      acc[i][j] = (floatx4){0.0f, 0.0f, 0.0f, 0.0f};

#define STAGE(BUF, KB)                                                      \
  do {                                                                      \
    gld_lds16(gA + (KB), &lA[BUF][ldst]);                                   \
    gld_lds16(gA + (KB) + (size_t)64 * KB2, &lA[BUF][4096 + ldst]);         \
    gld_lds16(gB + (KB), &lB[BUF][ldst]);                                   \
    gld_lds16(gB + (KB) + (size_t)64 * KB2, &lB[BUF][4096 + ldst]);         \
  } while (0)

#define COMPUTE(BUF)                                                        \
  do {                                                                      \
    intx8 a8[4];                                                            \
    _Pragma("unroll")                                                       \
    for (int i = 0; i < 4; ++i) {                                           \
      intx4 lo = *(const intx4*)&lA[BUF][offA[i]];                          \
      a8[i] = (intx8){lo[0], lo[1], lo[2], lo[3], 0, 0, 0, 0};              \
    }                                                                       \
    _Pragma("unroll")                                                       \
    for (int j = 0; j < 4; ++j) {                                           \
      intx4 lo = *(const intx4*)&lB[BUF][offB[j]];                          \
      intx8 b8 = (intx8){lo[0], lo[1], lo[2], lo[3], 0, 0, 0, 0};           \
      _Pragma("unroll")                                                     \
      for (int i = 0; i < 4; ++i)                                           \
        acc[i][j] = __builtin_amdgcn_mfma_scale_f32_16x16x128_f8f6f4(       \
            a8[i], b8, acc[i][j], 4, 4, 0, 0x7F7F7F7F, 0, 0x7F7F7F7F);      \
    }                                                                       \
  } while (0)

  // prologue: fill buffer 0 (k-bytes [0,64) of each row)
  STAGE(0, 0);
  __syncthreads();

  // 16 double-steps of 2x128 K. Stage next half-tile into the OTHER buffer
  // BEFORE computing the current one; one barrier (vmcnt+lgkm drain) per half.
  for (int kt = 0; kt < K_DIM; kt += 256) {
    const size_t kb = (size_t)(kt >> 1);
    STAGE(1, kb + 64);               // kt+128 always < K_DIM here
    COMPUTE(0);
    __syncthreads();
    if (kt + 256 < K_DIM) STAGE(0, kb + 128);
    COMPUTE(1);
    __syncthreads();
  }
#undef STAGE
#undef COMPUTE

  const float scale = (float)(*accd * (1.0 / (double)((size_t)M_DIM * K_DIM)));

  // C/D layout (shape-determined, dtype-independent): col = lane&15, row = quad*4 + reg
  #pragma unroll
  for (int j = 0; j < 4; ++j) {
    const int col = bN + waveN + j * 16 + m16;
    const float bj = bias[col];
    #pragma unroll
    for (int i = 0; i < 4; ++i) {
      const size_t row0 = (size_t)(bM + waveM + i * 16 + quad * 4);
      float* po = out + row0 * N_DIM + col;
      #pragma unroll
      for (int r = 0; r < 4; ++r)
        po[(size_t)r * N_DIM] = (acc[i][j][r] + bj) * scale;
    }
  }
}

extern "C" void kernel_launch(void* const* d_in, const int* in_sizes, int n_in,
                              void* d_out, int out_size, void* d_ws, size_t ws_size,
                              hipStream_t stream) {
  const float* x = (const float*)d_in[0];   // [8192, 4096]
  const float* W = (const float*)d_in[1];   // [4096, 4096]
  const float* b = (const float*)d_in[2];   // [4096]
  float* out = (float*)d_out;               // [8192, 4096]

  double* accd = (double*)d_ws;                                   // 8B |x| sum
  char* Xb = (char*)d_ws + 256;                                   // 16 MiB sign(x) fp4
  char* Wb = (char*)d_ws + 256 + (size_t)M_DIM * K_DIM / 2;       // 8 MiB sign(W) fp4

  hipMemsetAsync(d_ws, 0, 8, stream);   // zero the reduction accumulator (ws is poisoned)
  pack_kernel<<<PACK_BLOCKS, 256, 0, stream>>>(x, W, (unsigned short*)Xb, accd);
  gemm_kernel<<<dim3(N_DIM / 128, M_DIM / 128), 256, 0, stream>>>(Xb, Wb, b, accd, out);
}

// Round 3
// 352.158 us; speedup vs baseline: 1.0665x; 1.0171x over previous
//
#include <hip/hip_runtime.h>

typedef int intx4 __attribute__((ext_vector_type(4)));
typedef int intx8 __attribute__((ext_vector_type(8)));
typedef float floatx4 __attribute__((ext_vector_type(4)));

#define M_DIM 8192
#define N_DIM 4096
#define K_DIM 4096
#define KB2 (K_DIM / 2)   // bytes per packed fp4 row

#define PACK_BLOCKS 2048
#define NF4_X ((size_t)M_DIM * K_DIM / 4)              // float4 count of x
#define NF4_TOT (NF4_X + (size_t)N_DIM * K_DIM / 4)    // + float4 count of W

// async global->LDS, 16B per lane. LDS dest is wave-uniform base + lane*16.
__device__ __forceinline__ void gld_lds16(const char* g, char* l) {
  __builtin_amdgcn_global_load_lds(
      (const __attribute__((address_space(1))) unsigned int*)g,
      (__attribute__((address_space(3))) unsigned int*)l,
      16, 0, 0);
}

// fp4 e2m1 sign nibble: +1 -> 0x2, -1 -> 0xA, 0 -> 0x0
__device__ __forceinline__ unsigned nib(float v) {
  return v > 0.0f ? 0x2u : (v < 0.0f ? 0xAu : 0x0u);
}

// Fully-coalesced pack: each lane-iteration reads ONE float4 (lanes contiguous
// -> 1KB per load instruction) and writes ONE ushort of 4 nibbles (lanes
// contiguous -> 128B per wave store). x occupies float4 indices [0, NF4_X),
// W the rest; packed outputs are contiguous (Wb directly follows Xb).
__global__ __launch_bounds__(256) void pack_kernel(const float* __restrict__ x,
                                                   const float* __restrict__ Wm,
                                                   unsigned short* __restrict__ pk,
                                                   double* __restrict__ accd) {
  const int t = threadIdx.x;
  const size_t stride = (size_t)PACK_BLOCKS * 256;
  const float4* __restrict__ X4 = (const float4*)x;
  const float4* __restrict__ W4 = (const float4*)Wm;
  float s = 0.0f;
  for (size_t i = (size_t)blockIdx.x * 256 + t; i < NF4_TOT; i += stride) {
    float4 v;
    if (i < NF4_X) {
      v = X4[i];
      s += fabsf(v.x) + fabsf(v.y) + fabsf(v.z) + fabsf(v.w);
    } else {
      v = W4[i - NF4_X];
    }
    pk[i] = (unsigned short)(nib(v.x) | (nib(v.y) << 4) | (nib(v.z) << 8) |
                             (nib(v.w) << 12));
  }
  #pragma unroll
  for (int off = 32; off > 0; off >>= 1) s += __shfl_down(s, off);
  __shared__ float sp[4];
  if ((t & 63) == 0) sp[t >> 6] = s;
  __syncthreads();
  if (t == 0) atomicAdd(accd, (double)(sp[0] + sp[1] + sp[2] + sp[3]));
}

// C = Xb (M x K, fp4) * Wb^T (N x K, fp4); out[m][n] = (dot + bias[n]) * scale
//
// 256x256 tile / 512 threads (8 waves, 2M x 4N) / per-wave 8x4 frags of
// 16x16x128 fp4 (unit scales). DEEP PIPELINE (T3+T4): 4 LDS tile-buffers,
// 3-tile prefetch lead, counted s_waitcnt vmcnt(12) — never drained to 0 in
// the main loop (rounds 0-2 proved the 2-buffer __syncthreads structure is
// the m97 ~28%-MfmaUtil plateau; counted vmcnt is the documented fix).
// All buffer indices compile-time (4x unrolled groups — round-1 lesson).
//
// Per tile (BK=128 -> 64B/row): stage(j+3) [4 gld_lds/thread];
// vmcnt(12) [retires tile j's 4, leaves j+1..j+3 in flight]; s_barrier;
// compute tile j [12 ds_read_b128 + 32 MFMA, setprio(1) around MFMA];
// s_barrier [frees buf j&3 for stage(j+4) next iteration].
//
// LDS layout per buffer (16 KB per matrix): row pairs interleaved into 128-B
// lines: addr(r, c) = (r>>1)*128 + c*32 + (r&1)*16, slot c of row r holds
// global 16B k-chunk g = (c + (r>>1)) & 3 (swizzle on the global source since
// global_load_lds dests are lane-linear). Measured 0 bank conflicts.
__global__ __launch_bounds__(512, 2) void gemm_kernel(const char* __restrict__ Xb,
                                                      const char* __restrict__ Wb,
                                                      const float* __restrict__ bias,
                                                      const double* __restrict__ accd,
                                                      float* __restrict__ out) {
  __shared__ __align__(16) char lA[4][16384];
  __shared__ __align__(16) char lB[4][16384];
  const int t = threadIdx.x;
  const int lane = t & 63;
  const int w = t >> 6;            // wave 0..7
  const int m16 = lane & 15;
  const int quad = lane >> 4;      // 0..3 -> k-chunk of 32 fp4 (16 B)
  const int bM = blockIdx.y * 256;
  const int bN = blockIdx.x * 256;
  const int waveM = (w >> 2) * 128;    // 0 or 128
  const int waveN = (w & 3) * 64;      // 0,64,128,192

  // staging: thread t covers local row srl in [0,128), 16B slot ssc, so LDS
  // addr(srl,ssc) == t*16 (lane-linear). Swizzle chunk g is identical for
  // srl and srl+128 (128 even), so it folds into the global base pointers.
  const int srl = 2 * (t >> 3) + (t & 1);
  const int ssc = (t >> 1) & 3;
  const int g0 = (ssc + (srl >> 1)) & 3;
  const char* gA = Xb + (size_t)(bM + srl) * KB2 + g0 * 16;
  const char* gB = Wb + (size_t)(bN + srl) * KB2 + g0 * 16;
  const int ldst = w * 1024;       // wave-uniform LDS dest offset

  // per-wave ds_read byte offsets — loop-invariant
  int offA[8], offB[4];
  #pragma unroll
  for (int i = 0; i < 8; ++i) {
    const int m = waveM + i * 16 + m16;
    offA[i] = (m >> 1) * 128 + (((quad - (m >> 1)) & 3)) * 32 + (m & 1) * 16;
  }
  #pragma unroll
  for (int j = 0; j < 4; ++j) {
    const int n = waveN + j * 16 + m16;
    offB[j] = (n >> 1) * 128 + (((quad - (n >> 1)) & 3)) * 32 + (n & 1) * 16;
  }

  floatx4 acc[8][4];
  #pragma unroll
  for (int i = 0; i < 8; ++i)
    #pragma unroll
    for (int j = 0; j < 4; ++j)
      acc[i][j] = (floatx4){0.0f, 0.0f, 0.0f, 0.0f};

#define STAGE(BUF, TILE)                                                    \
  do {                                                                      \
    const size_t kb = (size_t)(TILE) * 64;                                  \
    gld_lds16(gA + kb, &lA[BUF][ldst]);                                     \
    gld_lds16(gA + kb + (size_t)128 * KB2, &lA[BUF][8192 + ldst]);          \
    gld_lds16(gB + kb, &lB[BUF][ldst]);                                     \
    gld_lds16(gB + kb + (size_t)128 * KB2, &lB[BUF][8192 + ldst]);          \
  } while (0)

#define COMPUTE(BUF)                                                        \
  do {                                                                      \
    intx8 b8[4];                                                            \
    _Pragma("unroll")                                                       \
    for (int j = 0; j < 4; ++j) {                                           \
      intx4 lo = *(const intx4*)&lB[BUF][offB[j]];                          \
      b8[j] = (intx8){lo[0], lo[1], lo[2], lo[3], 0, 0, 0, 0};              \
    }                                                                       \
    __builtin_amdgcn_s_setprio(1);                                          \
    _Pragma("unroll")                                                       \
    for (int i = 0; i < 8; ++i) {                                           \
      intx4 lo = *(const intx4*)&lA[BUF][offA[i]];                          \
      intx8 a8 = (intx8){lo[0], lo[1], lo[2], lo[3], 0, 0, 0, 0};           \
      _Pragma("unroll")                                                     \
      for (int j = 0; j < 4; ++j)                                           \
        acc[i][j] = __builtin_amdgcn_mfma_scale_f32_16x16x128_f8f6f4(       \
            a8, b8[j], acc[i][j], 4, 4, 0, 0x7F7F7F7F, 0, 0x7F7F7F7F);      \
    }                                                                       \
    __builtin_amdgcn_s_setprio(0);                                          \
  } while (0)

// counted vmcnt: "memory" clobber pins LDS reads/stage issues on each side
#define WAITV(N) asm volatile("s_waitcnt vmcnt(" #N ")" ::: "memory")
#define FENCE() asm volatile("" ::: "memory")
#define BAR() __builtin_amdgcn_s_barrier()

  // prologue: stage tiles 0,1,2 into buffers 0,1,2 (12 loads in flight)
  STAGE(0, 0);
  STAGE(1, 1);
  STAGE(2, 2);

  // steady state: tiles 0..27 (groups of 4, static buffer indices).
  // vmcnt(12) = 4 loads/tile x 3 tiles of lead kept in flight.
  for (int b = 0; b < 28; b += 4) {
    STAGE(3, b + 3); WAITV(12); BAR(); FENCE(); COMPUTE(0); FENCE(); BAR();
    STAGE(0, b + 4); WAITV(12); BAR(); FENCE(); COMPUTE(1); FENCE(); BAR();
    STAGE(1, b + 5); WAITV(12); BAR(); FENCE(); COMPUTE(2); FENCE(); BAR();
    STAGE(2, b + 6); WAITV(12); BAR(); FENCE(); COMPUTE(3); FENCE(); BAR();
  }
  // tail: tiles 28..31 — prefetch drains 12 -> 8 -> 4 -> 0
  STAGE(3, 31); WAITV(12); BAR(); FENCE(); COMPUTE(0); FENCE(); BAR();
  WAITV(8);  BAR(); FENCE(); COMPUTE(1); FENCE(); BAR();
  WAITV(4);  BAR(); FENCE(); COMPUTE(2); FENCE(); BAR();
  WAITV(0);  BAR(); FENCE(); COMPUTE(3);
#undef STAGE
#undef COMPUTE
#undef WAITV
#undef FENCE
#undef BAR

  const float scale = (float)(*accd * (1.0 / (double)((size_t)M_DIM * K_DIM)));

  // C/D layout (shape-determined): col = lane&15, row = quad*4 + reg
  #pragma unroll
  for (int j = 0; j < 4; ++j) {
    const int col = bN + waveN + j * 16 + m16;
    const float bj = bias[col];
    #pragma unroll
    for (int i = 0; i < 8; ++i) {
      const size_t row0 = (size_t)(bM + waveM + i * 16 + quad * 4);
      float* po = out + row0 * N_DIM + col;
      #pragma unroll
      for (int r = 0; r < 4; ++r)
        po[(size_t)r * N_DIM] = (acc[i][j][r] + bj) * scale;
    }
  }
}

extern "C" void kernel_launch(void* const* d_in, const int* in_sizes, int n_in,
                              void* d_out, int out_size, void* d_ws, size_t ws_size,
                              hipStream_t stream) {
  const float* x = (const float*)d_in[0];   // [8192, 4096]
  const float* W = (const float*)d_in[1];   // [4096, 4096]
  const float* b = (const float*)d_in[2];   // [4096]
  float* out = (float*)d_out;               // [8192, 4096]

  double* accd = (double*)d_ws;                                   // 8B |x| sum
  char* Xb = (char*)d_ws + 256;                                   // 16 MiB sign(x) fp4
  char* Wb = (char*)d_ws + 256 + (size_t)M_DIM * K_DIM / 2;       // 8 MiB sign(W) fp4

  hipMemsetAsync(d_ws, 0, 8, stream);   // zero the reduction accumulator (ws is poisoned)
  pack_kernel<<<PACK_BLOCKS, 256, 0, stream>>>(x, W, (unsigned short*)Xb, accd);
  gemm_kernel<<<dim3(N_DIM / 256, M_DIM / 256), 512, 0, stream>>>(Xb, Wb, b, accd, out);
}